// Round 5
// baseline (304.697 us; speedup 1.0000x reference)
//
#include <hip/hip_runtime.h>

#define B_    4
#define N_    11
#define D_    589824L      // 64*96*96 floats per row
#define PRF   590848L      // padded row stride = D_ + 1024 floats (+4 KiB) -> breaks 2^17 aliasing
#define NP2   66           // upper-tri incl diagonal (e2 pairs)
#define NP1   55           // strict upper-tri (e1 pairs)
#define NSH   4            // atomic shards (cuts per-address contention 4x)
#define GXR   576          // column segments per batch (1024 floats each)
#define E1W0  12           // e1 pairs owned by wave0 in reduce (VALU balance: 66*4+12*8 vs 43*8)

typedef float nfloat4 __attribute__((ext_vector_type(4)));

// ---------------------------------------------------------------------------
// wave64 sum-reduction via DPP (pure VALU). Result valid in lane 63. (proven r1-r4)
// ---------------------------------------------------------------------------
__device__ __forceinline__ float wave_red_add(float x) {
    int t;
    t = __builtin_amdgcn_update_dpp(0, __float_as_int(x), 0x111, 0xf, 0xf, false); x += __int_as_float(t);
    t = __builtin_amdgcn_update_dpp(0, __float_as_int(x), 0x112, 0xf, 0xf, false); x += __int_as_float(t);
    t = __builtin_amdgcn_update_dpp(0, __float_as_int(x), 0x114, 0xf, 0xf, false); x += __int_as_float(t);
    t = __builtin_amdgcn_update_dpp(0, __float_as_int(x), 0x118, 0xf, 0xf, false); x += __int_as_float(t);
    t = __builtin_amdgcn_update_dpp(0, __float_as_int(x), 0x142, 0xa, 0xf, false); x += __int_as_float(t);
    t = __builtin_amdgcn_update_dpp(0, __float_as_int(x), 0x143, 0xc, 0xf, false); x += __int_as_float(t);
    return x;
}

// ---------------------------------------------------------------------------
// K0: linear streaming copy x -> padded workspace. NT loads (x read once,
// keep L3 for ws); plain stores (we WANT ws L3-resident for K1/K3).
// grid (GXR, B_*N_): block = one 1024-float segment of one row.
// ---------------------------------------------------------------------------
__global__ __launch_bounds__(256) void copy_kernel(const float* __restrict__ x,
                                                   float* __restrict__ wsx) {
    const long row = blockIdx.y;                       // 0..43, x rows are contiguous
    const long off = (long)blockIdx.x * 1024 + threadIdx.x * 4;
    const nfloat4 v = __builtin_nontemporal_load(
        reinterpret_cast<const nfloat4*>(x + row * D_ + off));
    *reinterpret_cast<nfloat4*>(wsx + row * PRF + off) = v;
}

// ---------------------------------------------------------------------------
// K1: pairwise reductions, barrier-free, TLP-driven.
// grid (GXR, B_), 128 threads (2 waves). Both waves read the SAME 64-lane
// column window (L1 dedup); pair ownership split so per-thread accs stay
// in registers: wave0 = 66 e2 + e1[0,12) (78 accs), wave1 = e1[12,55) (43).
// 4 column sub-iters amortize the DPP tail. Atomics 4-way sharded by c&3.
// ---------------------------------------------------------------------------
__global__ __launch_bounds__(128) void reduce_kernel(const float* __restrict__ src, long rs,
                                                     double* __restrict__ e2s,   // [NSH][B_][NP2]
                                                     double* __restrict__ e1s) { // [NSH][B_][NP1]
    const int b = blockIdx.y, c = blockIdx.x;
    const int t = threadIdx.x, wave = t >> 6, lane = t & 63;
    const int sh = c & (NSH - 1);
    const float* sb = src + (long)b * N_ * rs;
    const long col0 = (long)c * 1024 + lane * 4;

    if (wave == 0) {
        float a2[NP2], a1[E1W0];
#pragma unroll
        for (int p = 0; p < NP2; ++p) a2[p] = 0.f;
#pragma unroll
        for (int p = 0; p < E1W0; ++p) a1[p] = 0.f;
#pragma unroll 1
        for (int it = 0; it < 4; ++it) {
            const long d = col0 + it * 256;
            float4 v[N_];
#pragma unroll
            for (int m = 0; m < N_; ++m)
                v[m] = *reinterpret_cast<const float4*>(sb + (long)m * rs + d);
            int p = 0;
#pragma unroll
            for (int i = 0; i < N_; ++i)
#pragma unroll
                for (int j = i; j < N_; ++j, ++p)
                    a2[p] += v[i].x * v[j].x + v[i].y * v[j].y +
                             v[i].z * v[j].z + v[i].w * v[j].w;
            int q = 0;
#pragma unroll
            for (int i = 0; i < N_; ++i)
#pragma unroll
                for (int j = i + 1; j < N_; ++j, ++q)
                    if (q < E1W0)
                        a1[q] += fabsf(v[i].x - v[j].x) + fabsf(v[i].y - v[j].y) +
                                 fabsf(v[i].z - v[j].z) + fabsf(v[i].w - v[j].w);
        }
#pragma unroll
        for (int p = 0; p < NP2; ++p) {
            const float s = wave_red_add(a2[p]);
            if (lane == 63) atomicAdd(&e2s[(sh * B_ + b) * NP2 + p], (double)s);
        }
#pragma unroll
        for (int p = 0; p < E1W0; ++p) {
            const float s = wave_red_add(a1[p]);
            if (lane == 63) atomicAdd(&e1s[(sh * B_ + b) * NP1 + p], (double)s);
        }
    } else {
        float a1[NP1 - E1W0];
#pragma unroll
        for (int p = 0; p < NP1 - E1W0; ++p) a1[p] = 0.f;
#pragma unroll 1
        for (int it = 0; it < 4; ++it) {
            const long d = col0 + it * 256;
            float4 v[N_];
#pragma unroll
            for (int m = 0; m < N_; ++m)
                v[m] = *reinterpret_cast<const float4*>(sb + (long)m * rs + d);
            int q = 0;
#pragma unroll
            for (int i = 0; i < N_; ++i)
#pragma unroll
                for (int j = i + 1; j < N_; ++j, ++q)
                    if (q >= E1W0)
                        a1[q - E1W0] += fabsf(v[i].x - v[j].x) + fabsf(v[i].y - v[j].y) +
                                        fabsf(v[i].z - v[j].z) + fabsf(v[i].w - v[j].w);
        }
#pragma unroll
        for (int p = 0; p < NP1 - E1W0; ++p) {
            const float s = wave_red_add(a1[p]);
            if (lane == 63) atomicAdd(&e1s[(sh * B_ + b) * NP1 + E1W0 + p], (double)s);
        }
    }
}

// ---------------------------------------------------------------------------
// K2: sum shards; E = e1*e2 (symmetric, diag 0); M = gamma*softmax(max-E) + I.
// ---------------------------------------------------------------------------
__global__ __launch_bounds__(128) void attn_kernel(const double* __restrict__ e2s,
                                                   const double* __restrict__ e1s,
                                                   const float* __restrict__ gamma,
                                                   float* __restrict__ Mws) {
    const int b = blockIdx.x, t = threadIdx.x;
    __shared__ double E[N_][N_];
    if (t < NP2) {
        int rem = t, i = 0, cnt = N_;
        while (rem >= cnt) { rem -= cnt; --cnt; ++i; }
        const int j = i + rem;
        double e = 0.0;
        if (j > i) {
            const int q = i * (2 * N_ - 1 - i) / 2 + (j - i - 1);
            double s2 = 0.0, s1 = 0.0;
#pragma unroll
            for (int sh = 0; sh < NSH; ++sh) {
                s2 += e2s[(sh * B_ + b) * NP2 + t];
                s1 += e1s[(sh * B_ + b) * NP1 + q];
            }
            e = s1 * s2;
        }
        E[i][j] = e;
        E[j][i] = e;
    }
    __syncthreads();
    if (t < N_) {
        const int i = t;
        double mn = E[i][0];
#pragma unroll
        for (int j = 1; j < N_; ++j) mn = fmin(mn, E[i][j]);
        double ex[N_], s = 0.0;
#pragma unroll
        for (int j = 0; j < N_; ++j) { ex[j] = exp(mn - E[i][j]); s += ex[j]; }
        const float g = gamma[0];
        const double inv = 1.0 / s;
#pragma unroll
        for (int j = 0; j < N_; ++j)
            Mws[(b * N_ + i) * N_ + j] = (float)(ex[j] * inv) * g + (i == j ? 1.0f : 0.0f);
    }
}

// ---------------------------------------------------------------------------
// K3: out[n,d] = sum_m M[n][m]*src[m,d]. Loop-free per thread: 11 loads
// (padded ws, L3-hot), 121 FMA, 11 NT stores. grid (GXR, B_), 256 threads.
// ---------------------------------------------------------------------------
__global__ __launch_bounds__(256) void apply_kernel(const float* __restrict__ src, long rs,
                                                    const float* __restrict__ Mws,
                                                    float* __restrict__ out) {
    const int b = blockIdx.y, c = blockIdx.x, t = threadIdx.x;
    __shared__ float M[N_ * N_];
    if (t < N_ * N_) M[t] = Mws[b * N_ * N_ + t];
    __syncthreads();

    const float* sb = src + (long)b * N_ * rs;
    float* ob = out + (long)b * N_ * D_;
    const long d = (long)c * 1024 + t * 4;

    float4 v[N_];
#pragma unroll
    for (int m = 0; m < N_; ++m)
        v[m] = *reinterpret_cast<const float4*>(sb + (long)m * rs + d);

#pragma unroll 1
    for (int n = 0; n < N_; ++n) {
        float ox = 0.f, oy = 0.f, oz = 0.f, ow = 0.f;
#pragma unroll
        for (int m = 0; m < N_; ++m) {
            const float w = M[n * N_ + m];
            ox += w * v[m].x; oy += w * v[m].y;
            oz += w * v[m].z; ow += w * v[m].w;
        }
        nfloat4 o; o[0] = ox; o[1] = oy; o[2] = oz; o[3] = ow;
        __builtin_nontemporal_store(o, reinterpret_cast<nfloat4*>(ob + (long)n * D_ + d));
    }
}

// ---------------------------------------------------------------------------
extern "C" void kernel_launch(void* const* d_in, const int* in_sizes, int n_in,
                              void* d_out, int out_size, void* d_ws, size_t ws_size,
                              hipStream_t stream) {
    const float* x     = (const float*)d_in[0];
    const float* gamma = (const float*)d_in[1];
    float* out         = (float*)d_out;

    const size_t HDR  = 32768;   // sharded fp64 accs (15.5 KB) + M (2 KB), 256B-aligned pad
    const size_t NEED = HDR + (size_t)B_ * N_ * PRF * sizeof(float);  // ~99.2 MiB

    double* e2s = (double*)d_ws;                      // [NSH][B_][NP2]
    double* e1s = e2s + NSH * B_ * NP2;               // [NSH][B_][NP1]
    float*  Mws = (float*)(e1s + NSH * B_ * NP1);     // [B_][121]
    float*  wsx = (float*)((char*)d_ws + HDR);        // padded copy of x

    // zero the fp64 accumulator shards (ws is poisoned before every launch)
    hipMemsetAsync(d_ws, 0, (size_t)(NSH * B_ * (NP2 + NP1)) * sizeof(double), stream);

    const float* src = x;
    long rs = D_;
    if (ws_size >= NEED) {
        copy_kernel<<<dim3(GXR, B_ * N_), 256, 0, stream>>>(x, wsx);
        src = wsx;
        rs = PRF;
    }

    reduce_kernel<<<dim3(GXR, B_), 128, 0, stream>>>(src, rs, e2s, e1s);
    attn_kernel<<<B_, 128, 0, stream>>>(e2s, e1s, gamma, Mws);
    apply_kernel<<<dim3(GXR, B_), 256, 0, stream>>>(src, rs, Mws, out);
}